// Round 3
// baseline (2636.624 us; speedup 1.0000x reference)
//
#include <hip/hip_runtime.h>
#include <hip/hip_bf16.h>

typedef __bf16 bf16_t;
typedef __bf16 bf16x8 __attribute__((ext_vector_type(8)));
typedef float floatx4 __attribute__((ext_vector_type(4)));

#define D_MODEL 768
#define D_INNER 1536
#define D_STATE 16
#define DT_RANK 48
#define NROWS 2048   /* B*L */
#define LSEQ 1024

// ---------------------------------------------------------------------------
// Input dtype detection: ln_w is all-ones. fp32 -> first word 0x3F800000,
// bf16 -> 0x3F803F80. flag: 1 = inputs are bf16, 0 = inputs are fp32.
// Round-2 evidence: flag==0 on this harness (inputs fp32).
// ---------------------------------------------------------------------------
__global__ void detect_kernel(const unsigned int* __restrict__ lnw, int* __restrict__ flag) {
  if (threadIdx.x == 0 && blockIdx.x == 0)
    *flag = (lnw[0] == 0x3F800000u) ? 0 : 1;
}

// Generic input->bf16 canonicalizer (uniform branch on *flagp).
__global__ __launch_bounds__(256) void cvt_kernel(const void* __restrict__ src,
                                                  bf16_t* __restrict__ dst, int n,
                                                  const int* __restrict__ flagp) {
  int i = blockIdx.x * 256 + threadIdx.x;
  if (i >= n) return;
  if (*flagp) dst[i] = ((const bf16_t*)src)[i];
  else        dst[i] = (bf16_t)(((const float*)src)[i]);
}

// ---------------------------------------------------------------------------
// Embedding gather: h (f32 residual stream) and hb (bf16 GEMM A-operand).
// ---------------------------------------------------------------------------
__global__ __launch_bounds__(256) void embed_kernel(const int* __restrict__ x,
                                                    const void* __restrict__ emb,
                                                    float* __restrict__ h,
                                                    bf16_t* __restrict__ hb,
                                                    const int* __restrict__ flagp) {
  int isbf = *flagp;
  int idx = blockIdx.x * 256 + threadIdx.x;           // 2048*768
  if (idx >= NROWS * D_MODEL) return;
  int row = idx / D_MODEL, c = idx - row * D_MODEL;
  size_t o = (size_t)x[row] * D_MODEL + c;
  float v = isbf ? (float)((const bf16_t*)emb)[o] : ((const float*)emb)[o];
  h[idx] = v;
  hb[idx] = (bf16_t)v;
}

// ---------------------------------------------------------------------------
// MFMA GEMM: C(M,N) = A(M,K) * Bw(N,K)^T. A always bf16. Bw bf16, unless
// flagp!=null and *flagp==0 -> Bw is fp32 (converted during LDS staging).
// 128x128 tile, BK=32, 4 waves x (64x64 = 4x4 MFMA 16x16x32).
// mode 0: Cf = acc (f32)          [in_proj -> xz]
// mode 1: v=acc+res; Cf=v, Cb=v   [out_proj + residual -> h, hb]
// mode 2: Cf = acc (f32)          [logits -- OUTPUT IS FP32]
// Layouts (m89/m91): A frag [m=lane&15][k=(lane>>4)*8+j], B mirrored n=lane&15,
// D col=lane&15, row=(lane>>4)*4+reg.
// ---------------------------------------------------------------------------
__global__ __launch_bounds__(256) void gemm_bt(const bf16_t* __restrict__ A,
                                               const void* __restrict__ Bw,
                                               int M, int N, int K, int mode,
                                               float* __restrict__ Cf,
                                               bf16_t* __restrict__ Cb,
                                               const float* __restrict__ res,
                                               const int* __restrict__ flagp) {
  __shared__ __align__(16) bf16_t As[128][40];  // 80B row stride: 16B-aligned, 2-way banks (free)
  __shared__ __align__(16) bf16_t Bs[128][40];
  int bNative = flagp ? (*flagp == 0) : 0;      // 1 -> Bw is fp32
  int tid = threadIdx.x;
  int m0 = blockIdx.y * 128, n0 = blockIdx.x * 128;
  int wave = tid >> 6, lane = tid & 63;
  int wr = wave >> 1, wc = wave & 1;
  int m16 = lane & 15, ksel = lane >> 4;

  floatx4 acc[4][4];
#pragma unroll
  for (int i = 0; i < 4; i++)
#pragma unroll
    for (int j = 0; j < 4; j++) acc[i][j] = (floatx4){0.f, 0.f, 0.f, 0.f};

  for (int k0 = 0; k0 < K; k0 += 32) {
#pragma unroll
    for (int rep = 0; rep < 2; ++rep) {
      int l = tid + rep * 256;
      int row = l >> 2, seg = l & 3;
      size_t offA = (size_t)(m0 + row) * K + k0 + seg * 8;
      *(uint4*)(&As[row][seg * 8]) = *(const uint4*)(A + offA);
      size_t offB = (size_t)(n0 + row) * K + k0 + seg * 8;
      if (!bNative) {
        *(uint4*)(&Bs[row][seg * 8]) = *(const uint4*)((const bf16_t*)Bw + offB);
      } else {
        const float* bf = (const float*)Bw + offB;
        float4 f0 = *(const float4*)bf;
        float4 f1 = *(const float4*)(bf + 4);
        bf16_t* d = &Bs[row][seg * 8];
        d[0] = (bf16_t)f0.x; d[1] = (bf16_t)f0.y; d[2] = (bf16_t)f0.z; d[3] = (bf16_t)f0.w;
        d[4] = (bf16_t)f1.x; d[5] = (bf16_t)f1.y; d[6] = (bf16_t)f1.z; d[7] = (bf16_t)f1.w;
      }
    }
    __syncthreads();
    bf16x8 aF[4], bF[4];
#pragma unroll
    for (int mi = 0; mi < 4; mi++)
      aF[mi] = *(const bf16x8*)(&As[wr * 64 + mi * 16 + m16][ksel * 8]);
#pragma unroll
    for (int ni = 0; ni < 4; ni++)
      bF[ni] = *(const bf16x8*)(&Bs[wc * 64 + ni * 16 + m16][ksel * 8]);
#pragma unroll
    for (int mi = 0; mi < 4; mi++)
#pragma unroll
      for (int ni = 0; ni < 4; ni++)
        acc[mi][ni] = __builtin_amdgcn_mfma_f32_16x16x32_bf16(aF[mi], bF[ni], acc[mi][ni], 0, 0, 0);
    __syncthreads();
  }

#pragma unroll
  for (int mi = 0; mi < 4; mi++)
#pragma unroll
    for (int ni = 0; ni < 4; ni++)
#pragma unroll
      for (int r = 0; r < 4; r++) {
        int row = m0 + wr * 64 + mi * 16 + ksel * 4 + r;
        int col = n0 + wc * 64 + ni * 16 + m16;
        size_t off = (size_t)row * N + col;
        float v = acc[mi][ni][r];
        if (mode == 0) {
          Cf[off] = v;
        } else if (mode == 1) {
          float o = v + res[off];
          Cf[off] = o;
          Cb[off] = (bf16_t)o;
        } else {
          Cf[off] = v;            // fp32 logits
        }
      }
}

// ---------------------------------------------------------------------------
// Depthwise causal conv1d (K=4) + bias + SiLU. x_in = xz[:, 0:1536] (f32).
// ---------------------------------------------------------------------------
__global__ __launch_bounds__(256) void conv_silu(const float* __restrict__ xz,
                                                 const bf16_t* __restrict__ cw,
                                                 const bf16_t* __restrict__ cb,
                                                 bf16_t* __restrict__ xc) {
  int idx = blockIdx.x * 256 + threadIdx.x;   // NROWS*D_INNER
  if (idx >= NROWS * D_INNER) return;
  int d = idx % D_INNER;
  int row = idx / D_INNER;
  int l = row % LSEQ;
  int base = row - l;                         // start row of this batch
  float s = (float)cb[d];
#pragma unroll
  for (int k = 0; k < 4; k++) {
    int ll = l - 3 + k;
    if (ll >= 0) s += (float)cw[d * 4 + k] * xz[(size_t)(base + ll) * (2 * D_INNER) + d];
  }
  float sil = s / (1.f + __expf(-s));
  xc[idx] = (bf16_t)sil;
}

// ---------------------------------------------------------------------------
// x_proj: x_dbl(2048,80) = xc(2048,1536) @ W(80,1536)^T. One block per row.
// ---------------------------------------------------------------------------
__device__ inline float bflo(unsigned int u) { return __uint_as_float(u << 16); }
__device__ inline float bfhi(unsigned int u) { return __uint_as_float(u & 0xffff0000u); }

__global__ __launch_bounds__(128) void xproj_kernel(const bf16_t* __restrict__ xc,
                                                    const bf16_t* __restrict__ W,
                                                    float* __restrict__ xdbl) {
  __shared__ unsigned int srow[D_INNER / 2];
  int row = blockIdx.x;
  const unsigned int* src = (const unsigned int*)(xc + (size_t)row * D_INNER);
  for (int i = threadIdx.x; i < D_INNER / 2; i += 128) srow[i] = src[i];
  __syncthreads();
  int j = threadIdx.x;
  if (j < DT_RANK + 2 * D_STATE) {
    const unsigned int* wr = (const unsigned int*)(W + (size_t)j * D_INNER);
    float s = 0.f;
    for (int i = 0; i < D_INNER / 2; i++) {
      unsigned int a = srow[i], w = wr[i];
      s = fmaf(bflo(a), bflo(w), s);
      s = fmaf(bfhi(a), bfhi(w), s);
    }
    xdbl[(size_t)row * 80 + j] = s;
  }
}

// ---------------------------------------------------------------------------
// dt_proj + softplus: dt(2048,1536) = softplus(x_dbl[:, :48] @ W(1536,48)^T + b)
// ---------------------------------------------------------------------------
__global__ __launch_bounds__(256) void dtproj_kernel(const float* __restrict__ xdbl,
                                                     const bf16_t* __restrict__ W,
                                                     const bf16_t* __restrict__ bias,
                                                     float* __restrict__ dt) {
  int idx = blockIdx.x * 256 + threadIdx.x;  // NROWS*D_INNER
  if (idx >= NROWS * D_INNER) return;
  int d = idx % D_INNER;
  int row = idx / D_INNER;
  const bf16_t* wr = W + (size_t)d * DT_RANK;
  const float* xr = xdbl + (size_t)row * 80;
  float s = (float)bias[d];
#pragma unroll 8
  for (int r = 0; r < DT_RANK; r++) s = fmaf(xr[r], (float)wr[r], s);
  float sp = (s > 20.f) ? s : log1pf(__expf(s));
  dt[idx] = sp;
}

// ---------------------------------------------------------------------------
// Selective scan fused with D-skip and SiLU(z) gating -> yg (bf16).
// One lane per (b,d,n); 16-lane xor-shuffle reduce over n.
// ---------------------------------------------------------------------------
__global__ __launch_bounds__(256) void scan_kernel(const float* __restrict__ dt,
                                                   const bf16_t* __restrict__ xc,
                                                   const float* __restrict__ xdbl,
                                                   const float* __restrict__ xz,
                                                   const bf16_t* __restrict__ A_log,
                                                   const bf16_t* __restrict__ Dp,
                                                   bf16_t* __restrict__ yg) {
  int tid = threadIdx.x;
  int chan = blockIdx.x * 16 + (tid >> 4);   // 0..3071
  int b = chan / D_INNER, d = chan % D_INNER;
  int n = tid & 15;
  float Adn = -__expf((float)A_log[d * D_STATE + n]);
  float Dd = (float)Dp[d];
  float h = 0.f;
  size_t baseRow = (size_t)b * LSEQ;
  for (int l = 0; l < LSEQ; l++) {
    size_t r = baseRow + l;
    float dtv = dt[r * D_INNER + d];
    float uv = (float)xc[r * D_INNER + d];
    float Bv = xdbl[r * 80 + DT_RANK + n];
    float Cv = xdbl[r * 80 + DT_RANK + D_STATE + n];
    float dA = __expf(dtv * Adn);
    h = fmaf(dA, h, dtv * Bv * uv);
    float p = h * Cv;
    p += __shfl_xor(p, 1, 16);
    p += __shfl_xor(p, 2, 16);
    p += __shfl_xor(p, 4, 16);
    p += __shfl_xor(p, 8, 16);
    if (n == 0) {
      float zv = xz[r * (2 * D_INNER) + D_INNER + d];
      float sil = zv / (1.f + __expf(-zv));
      float y = (p + Dd * uv) * sil;
      yg[r * D_INNER + d] = (bf16_t)y;
    }
  }
}

// ---------------------------------------------------------------------------
// LayerNorm over 768, bf16 out (logits A-operand).
// ---------------------------------------------------------------------------
__global__ __launch_bounds__(256) void ln_kernel(const float* __restrict__ h,
                                                 const bf16_t* __restrict__ w,
                                                 const bf16_t* __restrict__ b,
                                                 bf16_t* __restrict__ out) {
  __shared__ float s1[4], s2[4];
  int row = blockIdx.x;
  int tid = threadIdx.x, lane = tid & 63, wave = tid >> 6;
  const float* hr = h + (size_t)row * D_MODEL;
  float a = 0.f, a2 = 0.f;
  for (int i = tid; i < D_MODEL; i += 256) {
    float v = hr[i];
    a += v; a2 += v * v;
  }
#pragma unroll
  for (int m = 32; m >= 1; m >>= 1) {
    a += __shfl_xor(a, m, 64);
    a2 += __shfl_xor(a2, m, 64);
  }
  if (lane == 0) { s1[wave] = a; s2[wave] = a2; }
  __syncthreads();
  float sum = s1[0] + s1[1] + s1[2] + s1[3];
  float sum2 = s2[0] + s2[1] + s2[2] + s2[3];
  float mu = sum / D_MODEL;
  float var = sum2 / D_MODEL - mu * mu;
  float inv = rsqrtf(var + 1e-5f);
  for (int i = tid; i < D_MODEL; i += 256)
    out[(size_t)row * D_MODEL + i] = (bf16_t)((hr[i] - mu) * inv * (float)w[i] + (float)b[i]);
}

// ---------------------------------------------------------------------------
extern "C" void kernel_launch(void* const* d_in, const int* in_sizes, int n_in,
                              void* d_out, int out_size, void* d_ws, size_t ws_size,
                              hipStream_t stream) {
  const int* x = (const int*)d_in[0];
  const void* emb = d_in[1];
  float* out = (float*)d_out;                    // OUTPUT IS FP32 (reference dtype)

  // --- scratch inside d_out (dead before the final logits GEMM writes it) ---
  // d_out = 2048*32000 fp32 = 262 MB; scratch uses the first 75.5 MB.
  char* ob = (char*)d_out;
  float* h = (float*)(ob + 0);                   //  6,291,456 B
  bf16_t* hb = (bf16_t*)(ob + 6291456);          //  3,145,728 B
  float* xz = (float*)(ob + 9437184);            // 25,165,824 B
  bf16_t* xc = (bf16_t*)(ob + 34603008);         //  6,291,456 B
  float* xdbl = (float*)(ob + 40894464);         //    655,360 B
  float* dt = (float*)(ob + 41549824);           // 12,582,912 B
  bf16_t* yg = (bf16_t*)(ob + 54132736);         //  6,291,456 B
  bf16_t* wk = (bf16_t*)(ob + 60424192);         // 15,086,592 B canonical bf16 weights
  // --- d_ws: logits A-operand (must survive logits GEMM) + dtype flag ---
  bf16_t* lno = (bf16_t*)d_ws;                   //  3,145,728 B
  int* flag = (int*)((char*)d_ws + 3145728);

  // canonical weight layout (element offsets into wk)
  bf16_t* c_inw  = wk + 0;          // 2*3072*768 = 4,718,592
  bf16_t* c_cw   = wk + 4718592;    // 12,288
  bf16_t* c_cb   = wk + 4730880;    // 3,072
  bf16_t* c_xpw  = wk + 4733952;    // 245,760
  bf16_t* c_dtw  = wk + 4979712;    // 147,456
  bf16_t* c_dtb  = wk + 5127168;    // 3,072
  bf16_t* c_alog = wk + 5130240;    // 49,152
  bf16_t* c_dp   = wk + 5179392;    // 3,072
  bf16_t* c_outw = wk + 5182464;    // 2,359,296
  bf16_t* c_lnw  = wk + 7541760;    // 768
  bf16_t* c_lnb  = wk + 7542528;    // 768

  detect_kernel<<<1, 64, 0, stream>>>((const unsigned int*)d_in[11], flag);

  struct { int idx; bf16_t* dst; int n; } cv[] = {
    {2, c_inw, 4718592}, {3, c_cw, 12288}, {4, c_cb, 3072}, {5, c_xpw, 245760},
    {6, c_dtw, 147456}, {7, c_dtb, 3072}, {8, c_alog, 49152}, {9, c_dp, 3072},
    {10, c_outw, 2359296}, {11, c_lnw, 768}, {12, c_lnb, 768}};
  for (auto& c : cv)
    cvt_kernel<<<(c.n + 255) / 256, 256, 0, stream>>>(d_in[c.idx], c.dst, c.n, flag);

  embed_kernel<<<(NROWS * D_MODEL + 255) / 256, 256, 0, stream>>>(x, emb, h, hb, flag);

  for (int i = 0; i < 2; i++) {
    gemm_bt<<<dim3(3072 / 128, NROWS / 128), 256, 0, stream>>>(
        hb, c_inw + (size_t)i * 2 * D_INNER * D_MODEL, NROWS, 2 * D_INNER, D_MODEL,
        0, xz, nullptr, nullptr, nullptr);
    conv_silu<<<(NROWS * D_INNER + 255) / 256, 256, 0, stream>>>(
        xz, c_cw + (size_t)i * D_INNER * 4, c_cb + (size_t)i * D_INNER, xc);
    xproj_kernel<<<NROWS, 128, 0, stream>>>(xc, c_xpw + (size_t)i * 80 * D_INNER, xdbl);
    dtproj_kernel<<<(NROWS * D_INNER + 255) / 256, 256, 0, stream>>>(
        xdbl, c_dtw + (size_t)i * D_INNER * DT_RANK, c_dtb + (size_t)i * D_INNER, dt);
    scan_kernel<<<(2 * D_INNER) / 16, 256, 0, stream>>>(
        dt, xc, xdbl, xz, c_alog + (size_t)i * D_INNER * D_STATE, c_dp + (size_t)i * D_INNER, yg);
    gemm_bt<<<dim3(D_MODEL / 128, NROWS / 128), 256, 0, stream>>>(
        yg, c_outw + (size_t)i * D_MODEL * D_INNER, NROWS, D_MODEL, D_INNER,
        1, h, hb, h, nullptr);
  }

  ln_kernel<<<NROWS, 256, 0, stream>>>(h, c_lnw, c_lnb, lno);

  // logits (fp32) = lno @ emb^T (emb in native dtype -> adaptive B staging)
  gemm_bt<<<dim3(32000 / 128, NROWS / 128), 256, 0, stream>>>(
      lno, emb, NROWS, 32000, D_MODEL, 2, out, nullptr, nullptr, flag);
}